// Round 4
// baseline (379.318 us; speedup 1.0000x reference)
//
#include <hip/hip_runtime.h>
#include <math.h>

typedef __attribute__((ext_vector_type(4))) float f32x4;
typedef __attribute__((ext_vector_type(2))) float f32x2;
typedef __attribute__((ext_vector_type(8))) short bf16x8;
typedef __attribute__((ext_vector_type(4))) short short4v;

#define EPSN 1e-12f
#define TN 32
#define YS 640   // Yt row stride in shorts (16 rows staged per pass)

__device__ inline short f2bf(float x) {
    union { float f; unsigned u; } v; v.f = x;
    unsigned r = v.u + 0x7fffu + ((v.u >> 16) & 1u);
    return (short)(r >> 16);
}
__device__ inline float bf2f(short s) {
    union { unsigned u; float f; } v;
    v.u = ((unsigned)(unsigned short)s) << 16;
    return v.f;
}
__device__ inline float wsum64(float v) {
#pragma unroll
    for (int m = 32; m > 0; m >>= 1) v += __shfl_xor(v, m);
    return v;
}
__device__ inline float wsum32(float v) {
    v += __shfl_xor(v, 1);
    v += __shfl_xor(v, 2);
    v += __shfl_xor(v, 4);
    v += __shfl_xor(v, 8);
    v += __shfl_xor(v, 16);
    return v;
}
__device__ inline float sigm(float x) { return 1.0f / (1.0f + __expf(-x)); }
__device__ inline float tanh_fast(float x) {
    float a = fabsf(x);
    float e = __expf(2.0f * a);
    float t = 1.0f - 2.0f / (e + 1.0f);
    return copysignf(t, x);
}

// ---- prep: W_f (256x256) + W_iou (384x256) -> bf16 fragment-linear B ----
__global__ void prep_B(const float* __restrict__ W_f, const float* __restrict__ W_iou,
                       short* __restrict__ Blin) {
    int t = blockIdx.x * 256 + threadIdx.x;
    if (t >= 8 * 40 * 64) return;
    int lane = t & 63;
    int jb = (t >> 6) % 40;
    int kb = (t >> 6) / 40;
    int j = jb * 16 + (lane & 15);
    int k = kb * 32 + ((lane >> 4) << 3);
    const float* src = (j < 256) ? (W_f + (size_t)j * 256 + k)
                                 : (W_iou + (size_t)(j - 256) * 256 + k);
    bf16x8 v;
#pragma unroll
    for (int e = 0; e < 8; ++e) v[e] = f2bf(src[e]);
    *(bf16x8*)(Blin + (size_t)t * 8) = v;
}

// ---- fused: gather -> bf16 MFMA GEMM (A:32x256, B:640x256^T) -> 2-pass epilogue
__global__ __launch_bounds__(512, 8) void tree_fused(
    const float* __restrict__ h_src, const float* __restrict__ c_src,
    const float* __restrict__ iou, const int* __restrict__ child_idx,
    const float* __restrict__ b_f, const float* __restrict__ b_iou,
    const float* __restrict__ sc_iou_p, const float* __restrict__ sc_c_p,
    const short* __restrict__ Blin, float* __restrict__ out) {
    // U phase 1-2: A tile, 32 rows x 512 B (bf16, XOR-swizzled) = 16384 B
    // U phase 3-4 (x2 passes): Y half-tile, 16 rows x 640 shorts = 20480 B
    __shared__ short U[16 * YS];
    __shared__ float biou_lds[384];
    __shared__ float h_n2[TN], iou_n2[TN];
    __shared__ int cc_lds[TN][2];

    const int tid = threadIdx.x;
    const int wave = tid >> 6;
    const int lane = tid & 63;
    const int nbase = blockIdx.x * TN;

    const float sc_iou = sc_iou_p[0];
    const float sc_c = sc_c_p[0];

    if (tid < 384) biou_lds[tid] = b_iou[tid];

    // ---------- phase 1: gather h -> A, h-norm, iou-norm, stash child idx ----------
    {
        const int child = lane >> 5;
        const int seg = lane & 31;
        int cix[4];
#pragma unroll
        for (int r = 0; r < 4; ++r)
            cix[r] = child_idx[(size_t)(nbase + wave + 8 * r) * 2 + child];
        f32x4 hv[4];
#pragma unroll
        for (int r = 0; r < 4; ++r)
            hv[r] = *(const f32x4*)(h_src + (size_t)cix[r] * 128 + seg * 4);
#pragma unroll
        for (int r = 0; r < 4; ++r) {
            const int nd = wave + 8 * r;
            const int node = nbase + nd;
            short4v a4;
            a4.x = f2bf(hv[r].x); a4.y = f2bf(hv[r].y);
            a4.z = f2bf(hv[r].z); a4.w = f2bf(hv[r].w);
            const int swz = (lane * 8) ^ ((nd & 7) << 4);
            *(short4v*)((char*)U + nd * 512 + swz) = a4;
            if (lane == 0) cc_lds[nd][0] = cix[r];
            if (lane == 32) cc_lds[nd][1] = cix[r];
            float hss = hv[r].x * hv[r].x + hv[r].y * hv[r].y
                      + hv[r].z * hv[r].z + hv[r].w * hv[r].w;
            // iou norm: 384 floats/node = f32x4 (lanes cover 0..255) + f32x2 (256..383)
            const f32x4 v4 = *(const f32x4*)(iou + (size_t)node * 384 + lane * 4);
            const f32x2 v2 = *(const f32x2*)(iou + (size_t)node * 384 + 256 + lane * 2);
            float iss = v4.x * v4.x + v4.y * v4.y + v4.z * v4.z + v4.w * v4.w
                      + v2.x * v2.x + v2.y * v2.y;
            hss = wsum64(hss);
            iss = wsum64(iss);
            if (lane == 0) { h_n2[nd] = hss; iou_n2[nd] = iss; }
        }
    }
    __syncthreads();

    // ---------- phase 2: MFMA main, Y[32][640] = A * B^T (+ b_f folded) ----------
    f32x4 acc[2][5];
    {
        const int colb = wave * 80 + (lane & 15);
#pragma unroll
        for (int jj = 0; jj < 5; ++jj) {
            const int col = colb + jj * 16;
            float bv = 0.0f;
            if (col < 256) bv = b_f[col];   // wave-uniform branch (16-aligned blocks)
            const f32x4 a = {bv, bv, bv, bv};
            acc[0][jj] = a;
            acc[1][jj] = a;
        }
    }
    const int arow = lane & 15;
    const int kgrp = lane >> 4;
#pragma unroll
    for (int kb = 0; kb < 8; ++kb) {
        bf16x8 af[2];
#pragma unroll
        for (int m = 0; m < 2; ++m) {
            const int row = arow + m * 16;
            const int bofs = (kb * 64 + kgrp * 16) ^ ((row & 7) << 4);
            af[m] = *(const bf16x8*)((const char*)U + row * 512 + bofs);
        }
#pragma unroll
        for (int jj = 0; jj < 5; ++jj) {
            const int jb = wave * 5 + jj;
            const bf16x8 bfr = *(const bf16x8*)(Blin + ((size_t)(kb * 40 + jb) * 64 + lane) * 8);
            acc[0][jj] = __builtin_amdgcn_mfma_f32_16x16x32_bf16(af[0], bfr, acc[0][jj], 0, 0, 0);
            acc[1][jj] = __builtin_amdgcn_mfma_f32_16x16x32_bf16(af[1], bfr, acc[1][jj], 0, 0, 0);
        }
    }

    // ---------- phases 3-4 twice: spill 16 rows, epilogue 16 nodes ----------
#pragma unroll
    for (int p = 0; p < 2; ++p) {
        __syncthreads();   // p=0: A reads drained; p=1: pass-0 Y reads drained
        // spill acc[p] (rows p*16..p*16+15 of Y), bf16, XOR-swizzled
#pragma unroll
        for (int jj = 0; jj < 5; ++jj) {
            const int col = wave * 80 + jj * 16 + (lane & 15);
            const int r0 = (lane >> 4) * 4;
#pragma unroll
            for (int r = 0; r < 4; ++r) {
                const int row = r0 + r;   // 0..15
                U[row * YS + (col ^ (((row >> 2) & 3) << 4))] = f2bf(acc[p][jj][r]);
            }
        }
        __syncthreads();

        // epilogue: 32 threads per node, 4 elements each
        const int ndl = tid >> 5;          // 0..15 (row in U)
        const int nd = p * 16 + ndl;       // node within tile
        const int q = tid & 31;
        const int h0 = q * 4;              // 0..124
        const int node = nbase + nd;

        const int c0i = cc_lds[nd][0];
        const int c1i = cc_lds[nd][1];
        const f32x4 c0v = *(const f32x4*)(c_src + (size_t)c0i * 128 + h0);
        const f32x4 c1v = *(const f32x4*)(c_src + (size_t)c1i * 128 + h0);

        const int swz = ((ndl >> 2) & 3) << 4;
        const short4v yf0 = *(const short4v*)&U[ndl * YS + (h0 ^ swz)];
        const short4v yf1 = *(const short4v*)&U[ndl * YS + ((128 + h0) ^ swz)];
        const short4v yi  = *(const short4v*)&U[ndl * YS + ((256 + h0) ^ swz)];
        const short4v yo  = *(const short4v*)&U[ndl * YS + ((384 + h0) ^ swz)];
        const short4v yu  = *(const short4v*)&U[ndl * YS + ((512 + h0) ^ swz)];

        float c0n2 = c0v.x * c0v.x + c0v.y * c0v.y + c0v.z * c0v.z + c0v.w * c0v.w;
        c0n2 = wsum32(c0n2);

        float cs[4];
        float csn2 = 0.f;
#pragma unroll
        for (int e = 0; e < 4; ++e) {
            const float f0 = sigm(bf2f(yf0[e]));   // b_f already folded into Y
            const float f1 = sigm(bf2f(yf1[e]));
            const float v = f0 * ((const float*)&c0v)[e] + f1 * ((const float*)&c1v)[e];
            cs[e] = v;
            csn2 += v * v;
        }
        csn2 = wsum32(csn2);

        const float s_iou = sc_iou * sqrtf(iou_n2[nd]) / fmaxf(sqrtf(h_n2[nd]), EPSN);
        const float rs = sc_c * sqrtf(c0n2) / fmaxf(sqrtf(csn2), EPSN);

        const f32x4 bi0 = *(const f32x4*)&biou_lds[h0];
        const f32x4 bi1 = *(const f32x4*)&biou_lds[128 + h0];
        const f32x4 bi2 = *(const f32x4*)&biou_lds[256 + h0];

        f32x4 outh, outc;
#pragma unroll
        for (int e = 0; e < 4; ++e) {
            const float iv = bf2f(yi[e]) * s_iou + ((const float*)&bi0)[e];
            const float ov = bf2f(yo[e]) * s_iou + ((const float*)&bi1)[e];
            const float uv = bf2f(yu[e]) * s_iou + ((const float*)&bi2)[e];
            const float cval = sigm(iv) * tanh_fast(uv) + cs[e] * rs;
            const float hval = sigm(ov) * tanh_fast(cval);
            ((float*)&outh)[e] = hval;
            ((float*)&outc)[e] = cval;
        }
        *(f32x4*)(out + (size_t)node * 256 + h0) = outh;
        *(f32x4*)(out + (size_t)node * 256 + 128 + h0) = outc;
    }
}

extern "C" void kernel_launch(void* const* d_in, const int* in_sizes, int n_in,
                              void* d_out, int out_size, void* d_ws, size_t ws_size,
                              hipStream_t stream) {
    const float* h_src = (const float*)d_in[0];
    const float* c_src = (const float*)d_in[1];
    const float* iou = (const float*)d_in[2];
    const int* cidx = (const int*)d_in[3];
    const float* W_f = (const float*)d_in[4];
    const float* b_f = (const float*)d_in[5];
    const float* W_iou = (const float*)d_in[6];
    const float* b_iou = (const float*)d_in[7];
    const float* s_iou = (const float*)d_in[8];
    const float* s_c = (const float*)d_in[9];
    float* out = (float*)d_out;
    short* Blin = (short*)d_ws;

    const int N = in_sizes[3] / 2;  // 200000
    hipLaunchKernelGGL(prep_B, dim3(80), dim3(256), 0, stream, W_f, W_iou, Blin);
    hipLaunchKernelGGL(tree_fused, dim3(N / TN), dim3(512), 0, stream,
                       h_src, c_src, iou, cidx, b_f, b_iou, s_iou, s_c, Blin, out);
}

// Round 5
// 281.016 us; speedup vs baseline: 1.3498x; 1.3498x over previous
//
#include <hip/hip_runtime.h>
#include <math.h>

typedef __attribute__((ext_vector_type(4))) float f32x4;
typedef __attribute__((ext_vector_type(2))) float f32x2;
typedef __attribute__((ext_vector_type(8))) short bf16x8;
typedef __attribute__((ext_vector_type(4))) short short4v;

#define EPSN 1e-12f
#define TN 32

__device__ inline short f2bf(float x) {
    union { float f; unsigned u; } v; v.f = x;
    unsigned r = v.u + 0x7fffu + ((v.u >> 16) & 1u);
    return (short)(r >> 16);
}
__device__ inline float bf2f(short s) {
    union { unsigned u; float f; } v;
    v.u = ((unsigned)(unsigned short)s) << 16;
    return v.f;
}
__device__ inline float wsum64(float v) {
#pragma unroll
    for (int m = 32; m > 0; m >>= 1) v += __shfl_xor(v, m);
    return v;
}
__device__ inline float wsum16(float v) {
    v += __shfl_xor(v, 1);
    v += __shfl_xor(v, 2);
    v += __shfl_xor(v, 4);
    v += __shfl_xor(v, 8);
    return v;
}
__device__ inline float sigm(float x) { return 1.0f / (1.0f + __expf(-x)); }
__device__ inline float tanh_fast(float x) {
    float a = fabsf(x);
    float e = __expf(2.0f * a);
    float t = 1.0f - 2.0f / (e + 1.0f);
    return copysignf(t, x);
}

// ---- prep: W_f (256x256) + W_iou (384x256) -> bf16 fragment-linear B ----
__global__ void prep_B(const float* __restrict__ W_f, const float* __restrict__ W_iou,
                       short* __restrict__ Blin) {
    int t = blockIdx.x * 256 + threadIdx.x;
    if (t >= 8 * 40 * 64) return;
    int lane = t & 63;
    int jb = (t >> 6) % 40;
    int kb = (t >> 6) / 40;
    int j = jb * 16 + (lane & 15);
    int k = kb * 32 + ((lane >> 4) << 3);
    const float* src = (j < 256) ? (W_f + (size_t)j * 256 + k)
                                 : (W_iou + (size_t)(j - 256) * 256 + k);
    bf16x8 v;
#pragma unroll
    for (int e = 0; e < 8; ++e) v[e] = f2bf(src[e]);
    *(bf16x8*)(Blin + (size_t)t * 8) = v;
}

// ---- fused: gather -> N-split bf16 MFMA GEMM -> 2-part epilogue ----
// LDS map (shorts): A region [0, 8192)  (32 rows x 256 shorts, XOR swizzled)
//                   F region [8192, 16384)  (32 rows x 256 shorts, Y cols 0..255)
//                   IOU region [0, 12288)   (32 rows x 384 shorts, Y cols 256..639;
//                                            written only after A and F are dead)
__global__ __launch_bounds__(512, 7) void tree_fused(
    const float* __restrict__ h_src, const float* __restrict__ c_src,
    const float* __restrict__ iou, const int* __restrict__ child_idx,
    const float* __restrict__ b_f, const float* __restrict__ b_iou,
    const float* __restrict__ sc_iou_p, const float* __restrict__ sc_c_p,
    const short* __restrict__ Blin, float* __restrict__ out) {
    __shared__ short U[16384];            // 32768 B
    __shared__ float h_n2[TN], iou_n2[TN];
    __shared__ int cc_lds[TN][2];

    const int tid = threadIdx.x;
    const int wave = tid >> 6;
    const int lane = tid & 63;
    const int nbase = blockIdx.x * TN;

    const float sc_iou = sc_iou_p[0];
    const float sc_c = sc_c_p[0];

    // ---------- phase 1: gather h -> A, h-norm, iou-norm, stash child idx ----------
    {
        const int child = lane >> 5;
        const int seg = lane & 31;
        int cix[4];
#pragma unroll
        for (int r = 0; r < 4; ++r)
            cix[r] = child_idx[(size_t)(nbase + wave + 8 * r) * 2 + child];
        f32x4 hv[4];
#pragma unroll
        for (int r = 0; r < 4; ++r)
            hv[r] = *(const f32x4*)(h_src + (size_t)cix[r] * 128 + seg * 4);
#pragma unroll
        for (int r = 0; r < 4; ++r) {
            const int nd = wave + 8 * r;
            const int node = nbase + nd;
            short4v a4;
            a4.x = f2bf(hv[r].x); a4.y = f2bf(hv[r].y);
            a4.z = f2bf(hv[r].z); a4.w = f2bf(hv[r].w);
            const int swz = (lane * 8) ^ ((nd & 7) << 4);
            *(short4v*)((char*)U + nd * 512 + swz) = a4;
            if (lane == 0) cc_lds[nd][0] = cix[r];
            if (lane == 32) cc_lds[nd][1] = cix[r];
            float hss = hv[r].x * hv[r].x + hv[r].y * hv[r].y
                      + hv[r].z * hv[r].z + hv[r].w * hv[r].w;
            const f32x4 v4 = *(const f32x4*)(iou + (size_t)node * 384 + lane * 4);
            const f32x2 v2 = *(const f32x2*)(iou + (size_t)node * 384 + 256 + lane * 2);
            float iss = v4.x * v4.x + v4.y * v4.y + v4.z * v4.z + v4.w * v4.w
                      + v2.x * v2.x + v2.y * v2.y;
            hss = wsum64(hss);
            iss = wsum64(iss);
            if (lane == 0) { h_n2[nd] = hss; iou_n2[nd] = iss; }
        }
    }
    __syncthreads();

    const int arow = lane & 15;
    const int kgrp = lane >> 4;
    const int nd = tid >> 4;          // epilogue node (row), 0..31
    const int h0 = (tid & 15) * 8;    // epilogue element base, 0..120

    // ---------- pass F: Y cols 0..255 (forget gates), b_f folded ----------
    {
        f32x4 accf[2][2];
#pragma unroll
        for (int jj = 0; jj < 2; ++jj) {
            const float bv = b_f[(wave * 2 + jj) * 16 + (lane & 15)];
            const f32x4 a = {bv, bv, bv, bv};
            accf[0][jj] = a;
            accf[1][jj] = a;
        }
#pragma unroll
        for (int kb = 0; kb < 8; ++kb) {
            bf16x8 af[2];
#pragma unroll
            for (int m = 0; m < 2; ++m) {
                const int row = arow + m * 16;
                const int bofs = (kb * 64 + kgrp * 16) ^ ((row & 7) << 4);
                af[m] = *(const bf16x8*)((const char*)U + row * 512 + bofs);
            }
#pragma unroll
            for (int jj = 0; jj < 2; ++jj) {
                const int jbg = wave * 2 + jj;   // 0..15
                const bf16x8 bfr = *(const bf16x8*)(Blin + ((size_t)(kb * 40 + jbg) * 64 + lane) * 8);
                accf[0][jj] = __builtin_amdgcn_mfma_f32_16x16x32_bf16(af[0], bfr, accf[0][jj], 0, 0, 0);
                accf[1][jj] = __builtin_amdgcn_mfma_f32_16x16x32_bf16(af[1], bfr, accf[1][jj], 0, 0, 0);
            }
        }
        // spill F half: rows m*16+(lane>>4)*4+r, cols (wave*2+jj)*16+(lane&15)
#pragma unroll
        for (int m = 0; m < 2; ++m)
#pragma unroll
            for (int jj = 0; jj < 2; ++jj) {
                const int col = (wave * 2 + jj) * 16 + (lane & 15);
                const int r0 = m * 16 + (lane >> 4) * 4;
#pragma unroll
                for (int r = 0; r < 4; ++r) {
                    const int row = r0 + r;
                    U[8192 + row * 256 + (col ^ (((row >> 2) & 3) << 4))] = f2bf(accf[m][jj][r]);
                }
            }
    }
    __syncthreads();   // F visible; A still intact

    // ---------- pass IOU GEMM (cols 256..639) ----------
    f32x4 accio[2][3];
#pragma unroll
    for (int m = 0; m < 2; ++m)
#pragma unroll
        for (int jj = 0; jj < 3; ++jj) accio[m][jj] = (f32x4){0.f, 0.f, 0.f, 0.f};
#pragma unroll
    for (int kb = 0; kb < 8; ++kb) {
        bf16x8 af[2];
#pragma unroll
        for (int m = 0; m < 2; ++m) {
            const int row = arow + m * 16;
            const int bofs = (kb * 64 + kgrp * 16) ^ ((row & 7) << 4);
            af[m] = *(const bf16x8*)((const char*)U + row * 512 + bofs);
        }
#pragma unroll
        for (int jj = 0; jj < 3; ++jj) {
            const int jbg = 16 + wave * 3 + jj;   // 16..39
            const bf16x8 bfr = *(const bf16x8*)(Blin + ((size_t)(kb * 40 + jbg) * 64 + lane) * 8);
            accio[0][jj] = __builtin_amdgcn_mfma_f32_16x16x32_bf16(af[0], bfr, accio[0][jj], 0, 0, 0);
            accio[1][jj] = __builtin_amdgcn_mfma_f32_16x16x32_bf16(af[1], bfr, accio[1][jj], 0, 0, 0);
        }
    }

    // ---------- epilogue part 1: forget gates + weighted cell sum ----------
    float csr[8];
    float s_iou;
    {
        const int c0i = cc_lds[nd][0];
        const int c1i = cc_lds[nd][1];
        float c0v[8], c1v[8];
        *(f32x4*)&c0v[0] = *(const f32x4*)(c_src + (size_t)c0i * 128 + h0);
        *(f32x4*)&c0v[4] = *(const f32x4*)(c_src + (size_t)c0i * 128 + h0 + 4);
        *(f32x4*)&c1v[0] = *(const f32x4*)(c_src + (size_t)c1i * 128 + h0);
        *(f32x4*)&c1v[4] = *(const f32x4*)(c_src + (size_t)c1i * 128 + h0 + 4);

        const int fsw = ((nd >> 2) & 3) << 4;
        const bf16x8 yf0 = *(const bf16x8*)&U[8192 + nd * 256 + (h0 ^ fsw)];
        const bf16x8 yf1 = *(const bf16x8*)&U[8192 + nd * 256 + ((128 + h0) ^ fsw)];

        float c0n2 = 0.f;
#pragma unroll
        for (int e = 0; e < 8; ++e) c0n2 += c0v[e] * c0v[e];
        c0n2 = wsum16(c0n2);

        float cs[8];
        float csn2 = 0.f;
#pragma unroll
        for (int e = 0; e < 8; ++e) {
            const float f0 = sigm(bf2f(yf0[e]));   // b_f folded into Y
            const float f1 = sigm(bf2f(yf1[e]));
            const float v = f0 * c0v[e] + f1 * c1v[e];
            cs[e] = v;
            csn2 += v * v;
        }
        csn2 = wsum16(csn2);

        const float rs = sc_c * sqrtf(c0n2) / fmaxf(sqrtf(csn2), EPSN);
#pragma unroll
        for (int e = 0; e < 8; ++e) csr[e] = cs[e] * rs;
        s_iou = sc_iou * sqrtf(iou_n2[nd]) / fmaxf(sqrtf(h_n2[nd]), EPSN);
    }
    __syncthreads();   // all A reads (IOU GEMM) and F reads (part 1) done

    // ---------- spill IOU half (rows x 384 shorts at U[0..12288)) ----------
#pragma unroll
    for (int m = 0; m < 2; ++m)
#pragma unroll
        for (int jj = 0; jj < 3; ++jj) {
            const int col = (wave * 3 + jj) * 16 + (lane & 15);   // 0..383
            const int r0 = m * 16 + (lane >> 4) * 4;
#pragma unroll
            for (int r = 0; r < 4; ++r) {
                const int row = r0 + r;
                U[row * 384 + (col ^ (((row >> 2) & 3) << 4))] = f2bf(accio[m][jj][r]);
            }
        }
    __syncthreads();

    // ---------- epilogue part 2: i/o/u gates -> h, c ----------
    {
        const int iosw = ((nd >> 2) & 3) << 4;
        const bf16x8 yi = *(const bf16x8*)&U[nd * 384 + (h0 ^ iosw)];
        const bf16x8 yo = *(const bf16x8*)&U[nd * 384 + ((128 + h0) ^ iosw)];
        const bf16x8 yu = *(const bf16x8*)&U[nd * 384 + ((256 + h0) ^ iosw)];

        float biv[24];
        *(f32x4*)&biv[0]  = *(const f32x4*)(b_iou + h0);
        *(f32x4*)&biv[4]  = *(const f32x4*)(b_iou + h0 + 4);
        *(f32x4*)&biv[8]  = *(const f32x4*)(b_iou + 128 + h0);
        *(f32x4*)&biv[12] = *(const f32x4*)(b_iou + 128 + h0 + 4);
        *(f32x4*)&biv[16] = *(const f32x4*)(b_iou + 256 + h0);
        *(f32x4*)&biv[20] = *(const f32x4*)(b_iou + 256 + h0 + 4);

        const int node = nbase + nd;
        f32x4 outh[2], outc[2];
#pragma unroll
        for (int e = 0; e < 8; ++e) {
            const float iv = bf2f(yi[e]) * s_iou + biv[e];
            const float ov = bf2f(yo[e]) * s_iou + biv[8 + e];
            const float uv = bf2f(yu[e]) * s_iou + biv[16 + e];
            const float cval = sigm(iv) * tanh_fast(uv) + csr[e];
            const float hval = sigm(ov) * tanh_fast(cval);
            ((float*)outh)[e] = hval;
            ((float*)outc)[e] = cval;
        }
        *(f32x4*)(out + (size_t)node * 256 + h0) = outh[0];
        *(f32x4*)(out + (size_t)node * 256 + h0 + 4) = outh[1];
        *(f32x4*)(out + (size_t)node * 256 + 128 + h0) = outc[0];
        *(f32x4*)(out + (size_t)node * 256 + 128 + h0 + 4) = outc[1];
    }
}

extern "C" void kernel_launch(void* const* d_in, const int* in_sizes, int n_in,
                              void* d_out, int out_size, void* d_ws, size_t ws_size,
                              hipStream_t stream) {
    const float* h_src = (const float*)d_in[0];
    const float* c_src = (const float*)d_in[1];
    const float* iou = (const float*)d_in[2];
    const int* cidx = (const int*)d_in[3];
    const float* W_f = (const float*)d_in[4];
    const float* b_f = (const float*)d_in[5];
    const float* W_iou = (const float*)d_in[6];
    const float* b_iou = (const float*)d_in[7];
    const float* s_iou = (const float*)d_in[8];
    const float* s_c = (const float*)d_in[9];
    float* out = (float*)d_out;
    short* Blin = (short*)d_ws;

    const int N = in_sizes[3] / 2;  // 200000
    hipLaunchKernelGGL(prep_B, dim3(80), dim3(256), 0, stream, W_f, W_iou, Blin);
    hipLaunchKernelGGL(tree_fused, dim3(N / TN), dim3(512), 0, stream,
                       h_src, c_src, iou, cidx, b_f, b_iou, s_iou, s_c, Blin, out);
}